// Round 1
// baseline (256.117 us; speedup 1.0000x reference)
//
#include <hip/hip_runtime.h>
#include <hip/hip_bf16.h>
#include <stdint.h>

#define S 2048
#define D 64
#define BH 32                      // B*H
#define NROWS (BH * S)             // 65536 rows of the mask / attn matrix
#define CTX_ELEMS (NROWS * D)      // 4194304 floats in context output

typedef __attribute__((ext_vector_type(8))) __bf16 bf16x8;
typedef __attribute__((ext_vector_type(4))) float f32x4;

// Kernel 1: per mask row -> count unmasked, write attn row (mask?0:1/cnt),
// and write bit-packed "unmasked" bits into the context region of d_out
// (exactly 16.78 MB; kernel 2 consumes then overwrites it).
__global__ __launch_bounds__(256) void k_mask(const int* __restrict__ mask,
                                              float* __restrict__ attn,
                                              uint32_t* packed) {
    const int r = blockIdx.x;           // global row 0..65535
    const int t = threadIdx.x;          // 0..255, each handles 8 elems
    const long base = (long)r * S + t * 8;

    const int4 m0 = *(const int4*)(mask + base);
    const int4 m1 = *(const int4*)(mask + base + 4);
    int v[8] = {m0.x, m0.y, m0.z, m0.w, m1.x, m1.y, m1.z, m1.w};

    unsigned byte = 0;
    int cnt = 0;
#pragma unroll
    for (int j = 0; j < 8; ++j) {
        unsigned u = (v[j] == 0) ? 1u : 0u;   // 1 = unmasked
        byte |= u << j;
        cnt += (int)u;
    }

    // wave(64) reduce, then cross-wave via LDS
#pragma unroll
    for (int off = 32; off > 0; off >>= 1) cnt += __shfl_down(cnt, off, 64);

    __shared__ int wsum[4];
    __shared__ unsigned char bts[256];
    bts[t] = (unsigned char)byte;
    if ((t & 63) == 0) wsum[t >> 6] = cnt;
    __syncthreads();

    const int total = wsum[0] + wsum[1] + wsum[2] + wsum[3];
    const float inv = (total > 0) ? (1.0f / (float)total) : 0.0f;

    float4 a0, a1;
    a0.x = (byte & 1u)   ? inv : 0.0f;
    a0.y = (byte & 2u)   ? inv : 0.0f;
    a0.z = (byte & 4u)   ? inv : 0.0f;
    a0.w = (byte & 8u)   ? inv : 0.0f;
    a1.x = (byte & 16u)  ? inv : 0.0f;
    a1.y = (byte & 32u)  ? inv : 0.0f;
    a1.z = (byte & 64u)  ? inv : 0.0f;
    a1.w = (byte & 128u) ? inv : 0.0f;
    *(float4*)(attn + base)     = a0;
    *(float4*)(attn + base + 4) = a1;

    if (t < 64) {
        uint32_t w = (uint32_t)bts[4 * t]
                   | ((uint32_t)bts[4 * t + 1] << 8)
                   | ((uint32_t)bts[4 * t + 2] << 16)
                   | ((uint32_t)bts[4 * t + 3] << 24);
        packed[(long)r * 64 + t] = w;   // bit i of word w_idx <-> k = w_idx*32+i
    }
}

// Kernel 2: context = (1/cnt) * bits @ V  via bf16 MFMA 16x16x32.
// Grid (S/128, BH); 4 waves; wave w owns rows [w*32, w*32+32), full N=64.
#define BM 128
__global__ __launch_bounds__(256) void k_ctx(const uint32_t* packed,
                                             const float* __restrict__ V,
                                             float* ctx) {
    const int qt = blockIdx.x;          // 0..15
    const int bh = blockIdx.y;          // 0..31
    const int t = threadIdx.x;
    const int lane = t & 63;
    const int w = t >> 6;               // wave id 0..3
    const int l15 = lane & 15;
    const int lk = lane >> 4;           // 0..3 k-group
    const long rowbase = (long)bh * S + qt * BM;

    __shared__ uint32_t pk[BM][65];     // +1 pad: conflict-free column reads
    __shared__ float invs[BM];
    __shared__ __align__(16) __bf16 Vs[64][40];  // [col][k], 80B rows (16B-aligned b128)

    // stage this block's packed rows (before we later overwrite them with ctx)
    for (int i = t; i < BM * 64; i += 256) {
        pk[i >> 6][i & 63] = packed[(rowbase + (i >> 6)) * 64 + (i & 63)];
    }
    __syncthreads();

    if (t < BM) {
        int c = 0;
#pragma unroll
        for (int i = 0; i < 64; ++i) c += __popc(pk[t][i]);
        invs[t] = (c > 0) ? (1.0f / (float)c) : 0.0f;
    }

    f32x4 acc[2][4];
#pragma unroll
    for (int a = 0; a < 2; ++a)
#pragma unroll
        for (int b = 0; b < 4; ++b) acc[a][b] = f32x4{0.f, 0.f, 0.f, 0.f};

    const int vcol = t & 63;            // V staging: column
    const int vkb = (t >> 6) * 8;       // V staging: k base (8 consecutive k)

    for (int kk = 0; kk < S / 32; ++kk) {
        __syncthreads();                // Vs safe to overwrite
        {   // stage V[kk*32 .. +32][0..64] fp32 -> Vs[col][k] bf16 (transposed)
            const float* vp = V + ((long)bh * S + kk * 32 + vkb) * 64 + vcol;
            bf16x8 vv;
#pragma unroll
            for (int j = 0; j < 8; ++j) vv[j] = (__bf16)vp[j * 64];
            *reinterpret_cast<bf16x8*>(&Vs[vcol][vkb]) = vv;
        }
        __syncthreads();

        // A fragments: row = l15 (per 16-row tile), k = kk*32 + lk*8 + j
        bf16x8 afrag[2];
#pragma unroll
        for (int mt = 0; mt < 2; ++mt) {
            const uint32_t dw = pk[w * 32 + mt * 16 + l15][kk];
            const unsigned bby = (dw >> (lk * 8)) & 0xFFu;
            union { uint32_t u[4]; bf16x8 v; } au;
#pragma unroll
            for (int p = 0; p < 4; ++p) {
                uint32_t lo = ((bby >> (2 * p)) & 1u) ? 0x3F80u : 0u;
                uint32_t hi = ((bby >> (2 * p + 1)) & 1u) ? 0x3F800000u : 0u;
                au.u[p] = lo | hi;
            }
            afrag[mt] = au.v;
        }

        // B fragments: col = nt*16 + l15, k = lk*8 + j  -> contiguous in Vs
#pragma unroll
        for (int nt = 0; nt < 4; ++nt) {
            bf16x8 bfrag = *reinterpret_cast<const bf16x8*>(&Vs[nt * 16 + l15][lk * 8]);
            acc[0][nt] = __builtin_amdgcn_mfma_f32_16x16x32_bf16(afrag[0], bfrag, acc[0][nt], 0, 0, 0);
            acc[1][nt] = __builtin_amdgcn_mfma_f32_16x16x32_bf16(afrag[1], bfrag, acc[1][nt], 0, 0, 0);
        }
    }

    // epilogue: C/D layout col = l15, row = lk*4 + ri (per guide, m89-verified)
#pragma unroll
    for (int mt = 0; mt < 2; ++mt) {
#pragma unroll
        for (int ri = 0; ri < 4; ++ri) {
            const int rloc = w * 32 + mt * 16 + lk * 4 + ri;
            const float iv = invs[rloc];
            const long orow = rowbase + rloc;
#pragma unroll
            for (int nt = 0; nt < 4; ++nt) {
                ctx[orow * 64 + nt * 16 + l15] = acc[mt][nt][ri] * iv;
            }
        }
    }
}

extern "C" void kernel_launch(void* const* d_in, const int* in_sizes, int n_in,
                              void* d_out, int out_size, void* d_ws, size_t ws_size,
                              hipStream_t stream) {
    (void)in_sizes; (void)n_in; (void)d_ws; (void)ws_size; (void)out_size;
    const float* V = (const float*)d_in[2];          // Q,K are provably unused
    const int* mask = (const int*)d_in[3];
    float* ctx = (float*)d_out;                      // output 0: [B,H,S,D]
    float* attn = (float*)d_out + (size_t)CTX_ELEMS; // output 1: [B,H,S,S]
    uint32_t* packed = (uint32_t*)d_out;             // scratch aliasing ctx region

    k_mask<<<NROWS, 256, 0, stream>>>(mask, attn, packed);
    k_ctx<<<dim3(S / BM, BH), 256, 0, stream>>>(packed, V, ctx);
}